// Round 6
// baseline (92.846 us; speedup 1.0000x reference)
//
#include <hip/hip_runtime.h>

// YOLO decode, MI355X. R6 = R5 (coalesced-output) + occupancy + swizzle:
//  - TS=32 positions/block -> cls LDS 32KB (+head 1.9KB) -> 4 blocks/CU
//    (R5 was 66.5KB -> 2 blocks/CU, OccupancyPercent 18.8 -> latency-bound).
//  - power-of-2 LDS row (64 quads = 1KB) with XOR quad swizzle qs = qch^(sl&7)
//    -> even bank spread on ds_write_b128 and ds_read_b128 (kills the 1.66M
//    conflicts from PROW=244's stride-20 aliasing).
//  - head fields staged to head[15][32] LDS; all phases 256-thread-uniform,
//    single barrier; conf threads recompute sigmoid(obj) locally (VALU cheap).

#define NCLS 80
#define NA   3
#define BB   32
#define WW   76
#define HH   76
#define WH   (WW*HH)          // 5776
#define PP   (WH*NA)          // 17328
#define TS   32               // positions per block
#define NTILE ((WH + TS - 1) / TS)   // 181 (last tile: 16 valid)
#define QROW 64               // quads per padded LDS row (1KB)

__global__ __launch_bounds__(256, 4) void yolo_decode_kernel(
    const float* __restrict__ in,       // (B, 255, W, H)
    const float* __restrict__ anchors,  // (2, 3) flat: [d*3 + a]
    float* __restrict__ boxes,          // (B, P, 4)
    float* __restrict__ conf,           // (B, P, 80)
    float* __restrict__ scores)         // (B, P)
{
    __shared__ float cls[TS * QROW * 4];   // 32 KB; row sl, quads XOR-swizzled
    __shared__ float head[15 * TS];        // [(a*5+f)*TS + sl], 1920 B

    const int t    = threadIdx.x;
    const int bid  = blockIdx.x;
    const int tile = bid % NTILE;
    const int b    = bid / NTILE;
    const int s0   = tile * TS;
    int valid = WH - s0; if (valid > TS) valid = TS;

    const float* bplane = in + (size_t)b * 255 * WH;

    // ---- stage head: 15 planes x TS positions = 480 coalesced dword loads ----
    #pragma unroll
    for (int it = 0; it < 2; ++it) {
        int u = it * 256 + t;
        if (u < 15 * TS) {
            int pl  = u >> 5;              // 0..14 = a*5 + f
            int sl  = u & (TS - 1);
            int slc = sl < valid ? sl : valid - 1;
            int a   = pl / 5;
            int f   = pl - a * 5;
            head[u] = bplane[(size_t)(a * 85 + f) * WH + s0 + slc];
        }
    }

    // ---- stage 240 class channels transposed: 60 ch-quads x 32 sl ----
    #pragma unroll
    for (int it = 0; it < 8; ++it) {
        int u = it * 256 + t;
        if (u < 60 * TS) {
            int qch = u >> 5;              // 0..59 == a*20 + c0/4
            int sl  = u & 31;
            int slc = sl < valid ? sl : valid - 1;
            int ch0 = qch * 4;
            int a   = ch0 / 80;
            int c0  = ch0 - a * 80;
            const float* gp = bplane + (size_t)(a * 85 + 5 + c0) * WH + s0 + slc;
            float v0 = gp[0];
            float v1 = gp[(size_t)1 * WH];
            float v2 = gp[(size_t)2 * WH];
            float v3 = gp[(size_t)3 * WH];
            int qs = qch ^ (sl & 7);       // bank swizzle
            *reinterpret_cast<float4*>(&cls[(sl * QROW + qs) * 4]) =
                make_float4(v0, v1, v2, v3);
        }
    }

    __syncthreads();

    // ---- boxes + scores: t < 96, lane-linear stores ----
    if (t < NA * TS) {
        int p  = t;                        // p = sl*3 + a
        int sl = p / 3;
        int a  = p - sl * 3;
        float tx = head[(a * 5 + 0) * TS + sl];
        float ty = head[(a * 5 + 1) * TS + sl];
        float tw = head[(a * 5 + 2) * TS + sl];
        float th = head[(a * 5 + 3) * TS + sl];
        float to = head[(a * 5 + 4) * TS + sl];

        int s = s0 + sl;
        int w = s / HH;
        int h = s - w * HH;
        float sx = 1.0f / (1.0f + __expf(-tx));
        float sy = 1.0f / (1.0f + __expf(-ty));
        float bx = (sx + (float)w) * (1.0f / WW);
        float by = (sy + (float)h) * (1.0f / HH);
        float bw = __expf(tw) * anchors[a];
        float bh = __expf(th) * anchors[3 + a];

        float mx = -1e30f;
        #pragma unroll
        for (int c4 = 0; c4 < 20; ++c4) {
            int qs = (a * 20 + c4) ^ (sl & 7);
            float4 v = *reinterpret_cast<const float4*>(&cls[(sl * QROW + qs) * 4]);
            mx = fmaxf(mx, fmaxf(fmaxf(v.x, v.y), fmaxf(v.z, v.w)));
        }
        float so = 1.0f / (1.0f + __expf(-to));
        float sc = so * (1.0f / (1.0f + __expf(-mx)));

        if (p < valid * 3) {
            float4 box = make_float4(bx - 0.5f * bw, by - 0.5f * bh,
                                     bx + 0.5f * bw, by + 0.5f * bh);
            *reinterpret_cast<float4*>(boxes + ((size_t)b * PP + s0 * 3 + p) * 4) = box;
            scores[(size_t)b * PP + s0 * 3 + p] = sc;
        }
    }

    // ---- conf: 96 p x 20 quads = 1920 quads, lane-linear 16B stores ----
    size_t cbase = ((size_t)b * PP + (size_t)s0 * 3) * NCLS;   // word offset
    int vq = valid * 60;
    #pragma unroll
    for (int it = 0; it < 8; ++it) {
        int q = it * 256 + t;
        if (q < vq) {
            int p  = q / 20;
            int u  = q - p * 20;
            int sl = p / 3;
            int a  = p - sl * 3;
            int qs = (a * 20 + u) ^ (sl & 7);
            float4 tv = *reinterpret_cast<const float4*>(&cls[(sl * QROW + qs) * 4]);
            float to = head[(a * 5 + 4) * TS + sl];
            float so = 1.0f / (1.0f + __expf(-to));
            float4 o;
            o.x = so / (1.0f + __expf(-tv.x));
            o.y = so / (1.0f + __expf(-tv.y));
            o.z = so / (1.0f + __expf(-tv.z));
            o.w = so / (1.0f + __expf(-tv.w));
            *reinterpret_cast<float4*>(conf + cbase + (size_t)q * 4) = o;
        }
    }
}

extern "C" void kernel_launch(void* const* d_in, const int* in_sizes, int n_in,
                              void* d_out, int out_size, void* d_ws, size_t ws_size,
                              hipStream_t stream) {
    const float* in      = (const float*)d_in[0];
    const float* anchors = (const float*)d_in[1];

    float* boxes  = (float*)d_out;                       // B*P*4
    float* conf   = boxes + (size_t)BB * PP * 4;         // B*P*80
    float* scores = conf + (size_t)BB * PP * NCLS;       // B*P

    int blocks = BB * NTILE;                             // 5792
    yolo_decode_kernel<<<blocks, 256, 0, stream>>>(in, anchors, boxes, conf, scores);
}

// Round 7
// 83.706 us; speedup vs baseline: 1.1092x; 1.1092x over previous
//
#include <hip/hip_runtime.h>

// YOLO decode, MI355X. R7 = R5 (82us, coalesced-output, TS=64) + two fixes:
//  - PROW 244 -> 260 words (1040B row stride): rows rotate banks by 4 words,
//    making staging ds_write_b128 and conf ds_read_b128 conflict-free
//    (R5 measured 1.66M conflict-cycles; R6's power-of-2 row made it worse).
//  - #pragma unroll 5 on the 15-iter staging/conf loops: <=20 global loads in
//    flight -> no VGPR spill (R5's full unroll, VGPR=88, is the suspected
//    source of its +44MB WRITE_SIZE = scratch traffic).

#define NCLS 80
#define NA   3
#define BB   32
#define WW   76
#define HH   76
#define WH   (WW*HH)          // 5776
#define PP   (WH*NA)          // 17328
#define TS   64               // positions per tile
#define NTILE ((WH + TS - 1) / TS)   // 91 (last tile: 16 valid)
#define PROW 260              // padded LDS row stride (words) = 1040B

__global__ __launch_bounds__(256, 2) void yolo_decode_kernel(
    const float* __restrict__ in,       // (B, 255, W, H)
    const float* __restrict__ anchors,  // (2, 3) flat: [d*3 + a]
    float* __restrict__ boxes,          // (B, P, 4)
    float* __restrict__ conf,           // (B, P, 80)
    float* __restrict__ scores)         // (B, P)
{
    __shared__ float  cls[TS * PROW];     // [s][a*80+c], 66560 B
    __shared__ float  so_buf[TS * NA];    // [p = s*3+a], 768 B
    __shared__ float4 box_buf[TS * NA];   // [p], 3072 B

    const int t    = threadIdx.x;
    const int bid  = blockIdx.x;
    const int tile = bid % NTILE;
    const int b    = bid / NTILE;
    const int s0   = tile * TS;
    int valid = WH - s0; if (valid > TS) valid = TS;

    const float* bplane = in + (size_t)b * 255 * WH;

    // ---- head loads (t<192): wave w handles anchor w, lanes = consecutive s ----
    int a_h  = t >> 6;           // 0..2 (wave 3 idle here)
    int sl_h = t & 63;
    int slc_h = sl_h < valid ? sl_h : valid - 1;
    float tx = 0.f, ty = 0.f, tw = 0.f, th = 0.f, to = 0.f;
    if (t < 192) {
        const float* hp = bplane + (size_t)(a_h * 85) * WH + s0 + slc_h;
        tx = hp[0];
        ty = hp[(size_t)1 * WH];
        tw = hp[(size_t)2 * WH];
        th = hp[(size_t)3 * WH];
        to = hp[(size_t)4 * WH];
    }

    // ---- stage 240 class channels transposed into LDS ----
    // unit = (ch-quad 0..59, sl 0..63); 3840 units, 15/thread.
    // Loads: lanes = consecutive sl of one plane -> fully coalesced dwords.
    // Write: one ds_write_b128 per unit into cls[sl][ch0..ch0+3].
    #pragma unroll 5
    for (int it = 0; it < 15; ++it) {
        int unit = it * 256 + t;
        int qch  = unit >> 6;          // 0..59
        int sl   = unit & 63;
        int slc  = sl < valid ? sl : valid - 1;
        int ch0  = qch * 4;            // 0..236 in a*80+c domain (never straddles a)
        int a    = ch0 / 80;
        int c0   = ch0 - a * 80;
        const float* gp = bplane + (size_t)(a * 85 + 5 + c0) * WH + s0 + slc;
        float v0 = gp[0];
        float v1 = gp[(size_t)1 * WH];
        float v2 = gp[(size_t)2 * WH];
        float v3 = gp[(size_t)3 * WH];
        *reinterpret_cast<float4*>(&cls[sl * PROW + ch0]) = make_float4(v0, v1, v2, v3);
    }

    // ---- head compute -> LDS bufs (t<192) ----
    if (t < 192) {
        int s = s0 + slc_h;
        int w = s / HH;
        int h = s - w * HH;
        float sx = 1.0f / (1.0f + __expf(-tx));
        float sy = 1.0f / (1.0f + __expf(-ty));
        float bx = (sx + (float)w) * (1.0f / WW);
        float by = (sy + (float)h) * (1.0f / HH);
        float bw = __expf(tw) * anchors[a_h];
        float bh = __expf(th) * anchors[3 + a_h];
        int p = slc_h * 3 + a_h;       // clamped dup writes store identical data
        box_buf[p] = make_float4(bx - 0.5f * bw, by - 0.5f * bh,
                                 bx + 0.5f * bw, by + 0.5f * bh);
        so_buf[p] = 1.0f / (1.0f + __expf(-to));
    }

    __syncthreads();

    // ---- conf: 3840 quads, 15/thread; stores lane-linear (1KB/wave/instr) ----
    size_t cbase = ((size_t)b * PP + (size_t)s0 * 3) * NCLS;   // word offset
    int vq = valid * 60;               // valid quads
    #pragma unroll 5
    for (int it = 0; it < 15; ++it) {
        int q  = it * 256 + t;
        int p  = q / 20;
        int u  = q - p * 20;
        int sl = p / 3;
        int a  = p - sl * 3;
        float4 tv = *reinterpret_cast<const float4*>(&cls[sl * PROW + a * 80 + u * 4]);
        float so = so_buf[p];
        float4 o;
        o.x = (1.0f / (1.0f + __expf(-tv.x))) * so;
        o.y = (1.0f / (1.0f + __expf(-tv.y))) * so;
        o.z = (1.0f / (1.0f + __expf(-tv.z))) * so;
        o.w = (1.0f / (1.0f + __expf(-tv.w))) * so;
        if (q < vq)
            *reinterpret_cast<float4*>(conf + cbase + (size_t)q * 4) = o;
    }

    // ---- boxes + scores (t<192), lane-linear stores ----
    if (t < 192) {
        int p = t;
        float4 bq = box_buf[p];
        if (p < valid * 3)
            *reinterpret_cast<float4*>(boxes + ((size_t)b * PP + s0 * 3 + p) * 4) = bq;

        int sl = p / 3;
        int a  = p - sl * 3;
        float mx = -1e30f;
        #pragma unroll
        for (int c4 = 0; c4 < 20; ++c4) {
            float4 v = *reinterpret_cast<const float4*>(&cls[sl * PROW + a * 80 + c4 * 4]);
            mx = fmaxf(mx, fmaxf(fmaxf(v.x, v.y), fmaxf(v.z, v.w)));
        }
        float sc = so_buf[p] * (1.0f / (1.0f + __expf(-mx)));
        if (p < valid * 3)
            scores[(size_t)b * PP + s0 * 3 + p] = sc;
    }
}

extern "C" void kernel_launch(void* const* d_in, const int* in_sizes, int n_in,
                              void* d_out, int out_size, void* d_ws, size_t ws_size,
                              hipStream_t stream) {
    const float* in      = (const float*)d_in[0];
    const float* anchors = (const float*)d_in[1];

    float* boxes  = (float*)d_out;                       // B*P*4
    float* conf   = boxes + (size_t)BB * PP * 4;         // B*P*80
    float* scores = conf + (size_t)BB * PP * NCLS;       // B*P

    int blocks = BB * NTILE;                             // 2912
    yolo_decode_kernel<<<blocks, 256, 0, stream>>>(in, anchors, boxes, conf, scores);
}